// Round 6
// baseline (344.843 us; speedup 1.0000x reference)
//
#include <hip/hip_runtime.h>

// BatchSplitFF: DM=1024, NE=16, ES=4 (NES=64 expert pairs), ESZ=64,
// BATCH*SEQ = 8*2048 tokens -> 1024 groups of 16 tokens.
#define DM   1024
#define NES  64
#define ESZ  64
#define NG   1024
#define TOK  16

typedef __bf16 bf16;
typedef __bf16 bf16x4 __attribute__((ext_vector_type(4)));
typedef __bf16 bf16x8 __attribute__((ext_vector_type(8)));
typedef float  f32x4  __attribute__((ext_vector_type(4)));

// async global->LDS, 16B per lane, LDS dest = wave-uniform base + lane*16
__device__ __forceinline__ void gld_lds16(const bf16* g, bf16* s) {
    __builtin_amdgcn_global_load_lds(
        (const __attribute__((address_space(1))) void*)g,
        (__attribute__((address_space(3))) void*)s, 16, 0, 0);
}

// ---------------- K01: fused weight-transpose + logits/argmax ----------------
// k0 and k1 are data-independent; fusing them co-schedules k0's memory-bound
// waves with k1's latency-stalled VALU waves on every CU (even blockIdx =
// k1-work, odd = k0-work, interleaved for per-CU mix). Both bodies are the
// VERBATIM round-2 passing versions (k1: 91.6 us standalone, bit-identical
// fp32 logits chain; round-5's LDS-staged ctrl variant was LDS-pipe-bound at
// 130 us and is reverted). Dynamic LDS = max(k0 tile 16.6KB, k1 12.8KB).
__global__ __launch_bounds__(256) void k01_fused(const float* __restrict__ x,
                                                 const float* __restrict__ ctrl,
                                                 const float* __restrict__ f1,
                                                 const float* __restrict__ f2,
                                                 bf16* __restrict__ f1p,
                                                 bf16* __restrict__ f2t,
                                                 int* __restrict__ sel,
                                                 unsigned* __restrict__ selp) {
    extern __shared__ __align__(16) char smem_raw[];
    const int tid = threadIdx.x;

    if (blockIdx.x & 1) {
        // ---------------- k0 body (verbatim round-2; bid remap) ----------------
        // f1 [d][es][f] -> f1p bf16 [es][f][d]; f2 [es][f][d] -> f2t bf16 [es][d][f]
        float* tile = (float*)smem_raw;          // 64*65 floats = 16.6 KB
        const int bid = blockIdx.x >> 1;
        const int es = bid >> 4, d0 = (bid & 15) * 64;
        #pragma unroll
        for (int i = 0; i < 4; ++i) {
            int idx = i * 256 + tid; int r = idx >> 4, c4 = (idx & 15) * 4;
            float4 v = *(const float4*)(f1 + (size_t)(d0 + r) * 4096 + es * 64 + c4);
            tile[r * 65 + c4] = v.x; tile[r * 65 + c4 + 1] = v.y;
            tile[r * 65 + c4 + 2] = v.z; tile[r * 65 + c4 + 3] = v.w;
        }
        __syncthreads();
        #pragma unroll
        for (int i = 0; i < 2; ++i) {
            int idx = i * 256 + tid; int f = idx >> 3, dl0 = (idx & 7) * 8;
            bf16x8 o;
            #pragma unroll
            for (int j = 0; j < 8; ++j) o[j] = (bf16)tile[(dl0 + j) * 65 + f];
            *(bf16x8*)(f1p + (size_t)es * 65536 + f * 1024 + d0 + dl0) = o;
        }
        __syncthreads();
        #pragma unroll
        for (int i = 0; i < 4; ++i) {
            int idx = i * 256 + tid; int r = idx >> 4, c4 = (idx & 15) * 4;
            float4 v = *(const float4*)(f2 + (size_t)es * 65536 + r * 1024 + d0 + c4);
            tile[r * 65 + c4] = v.x; tile[r * 65 + c4 + 1] = v.y;
            tile[r * 65 + c4 + 2] = v.z; tile[r * 65 + c4 + 3] = v.w;
        }
        __syncthreads();
        #pragma unroll
        for (int i = 0; i < 2; ++i) {
            int idx = i * 256 + tid; int dl = idx >> 3, f0 = (idx & 7) * 8;
            bf16x8 o;
            #pragma unroll
            for (int j = 0; j < 8; ++j) o[j] = (bf16)tile[(f0 + j) * 65 + dl];
            *(bf16x8*)(f2t + (size_t)es * 65536 + (size_t)(d0 + dl) * 64 + f0) = o;
        }
    } else {
        // ---------------- k1 body (verbatim round-2, 91.6 us proven) ----------
        // fp32 logits + argmax + sel nibble-pack. Per-(t,es) chain: single fmac
        // per term, d strictly ascending -> BIT-IDENTICAL logits to all passing
        // rounds. ctrl read via coalesced VMEM (L2-hit) -- NOT LDS (round-5's
        // LDS-ctrl variant overloaded the one-per-CU LDS pipe and regressed).
        float* xs = (float*)smem_raw;            // TOK*132 floats = 8448 B
        float* sl = xs + TOK * 132;              // TOK*NES floats = 4096 B
        int*   st = (int*)(sl + TOK * NES);      // NES ints = 256 B
        const int bg  = blockIdx.x >> 1;
        const int es  = tid & 63;
        const int tq  = tid >> 6;            // wave 0..3 -> rows tq*4 .. tq*4+3
        const float* xg = x + (size_t)bg * (TOK * DM);
        const float* cp = ctrl + es;
        float acc[4] = {0.f, 0.f, 0.f, 0.f};
        for (int d0 = 0; d0 < DM; d0 += 128) {
            __syncthreads();
            #pragma unroll
            for (int c = 0; c < 2; ++c) {    // stage 16 x 128 chunk (coalesced)
                int idx = tid + c * 256;
                int tr  = idx >> 5;
                int c4  = (idx & 31) * 4;
                float4 v = *(const float4*)(xg + tr * DM + d0 + c4);
                *(float4*)(xs + tr * 132 + c4) = v;
            }
            __syncthreads();
            #pragma unroll 2
            for (int dl4 = 0; dl4 < 128; dl4 += 4) {
                float4 v0 = *(const float4*)(xs + (tq * 4 + 0) * 132 + dl4);
                float4 v1 = *(const float4*)(xs + (tq * 4 + 1) * 132 + dl4);
                float4 v2 = *(const float4*)(xs + (tq * 4 + 2) * 132 + dl4);
                float4 v3 = *(const float4*)(xs + (tq * 4 + 3) * 132 + dl4);
                float c0 = cp[(size_t)(d0 + dl4 + 0) * 64];
                float c1 = cp[(size_t)(d0 + dl4 + 1) * 64];
                float c2 = cp[(size_t)(d0 + dl4 + 2) * 64];
                float c3 = cp[(size_t)(d0 + dl4 + 3) * 64];
                acc[0] += v0.x * c0; acc[1] += v1.x * c0;
                acc[2] += v2.x * c0; acc[3] += v3.x * c0;
                acc[0] += v0.y * c1; acc[1] += v1.y * c1;
                acc[2] += v2.y * c1; acc[3] += v3.y * c1;
                acc[0] += v0.z * c2; acc[1] += v1.z * c2;
                acc[2] += v2.z * c2; acc[3] += v3.z * c2;
                acc[0] += v0.w * c3; acc[1] += v1.w * c3;
                acc[2] += v2.w * c3; acc[3] += v3.w * c3;
            }
        }
        #pragma unroll
        for (int i = 0; i < 4; ++i) {
            int t = tq * 4 + i;
            sl[t * NES + es] = acc[i] + (float)t * (1e-6f / 15.f);
        }
        __syncthreads();
        if (tid < NES) {
            float best = -1e30f; int bi = 0;
            #pragma unroll
            for (int t = 0; t < TOK; ++t) {
                float v = sl[t * NES + tid];
                if (v >= best) { best = v; bi = t; }   // >= : later t wins ties
            }
            sel[bg * NES + tid] = bi;
            st[tid] = bi;
        }
        __syncthreads();
        if (tid < 8) {   // pack 8 es per dword, 4-bit each
            unsigned p = 0;
            #pragma unroll
            for (int k = 0; k < 8; ++k) p |= (unsigned)st[tid * 8 + k] << (4 * k);
            selp[bg * 8 + tid] = p;
        }
    }
}

// ---------------- K2: FFN1 (gather + GEMM + bias + relu) ----------------
// Exact round-2 version.
__global__ __launch_bounds__(256) void k2_ffn1(const float* __restrict__ x,
                                               const bf16* __restrict__ f1p,
                                               const float* __restrict__ bias,
                                               const int* __restrict__ sel,
                                               bf16* __restrict__ inner) {
    __shared__ int  sel_s[128];
    __shared__ __align__(16) bf16 As[128 * 40];
    __shared__ __align__(16) bf16 Bs[64 * 40];
    const int es  = blockIdx.y;
    const int g0  = blockIdx.x * 128;
    const int tid = threadIdx.x;
    if (tid < 128) sel_s[tid] = sel[(g0 + tid) * 64 + es];
    __syncthreads();

    const int w = tid >> 6, l = tid & 63, quad = l >> 4, lr = l & 15;
    int tokrow[4];
    #pragma unroll
    for (int p = 0; p < 4; ++p) {
        int grow = p * 32 + (tid >> 3);
        tokrow[p] = (g0 + grow) * 16 + sel_s[grow];
    }
    const int c4 = (tid & 7) * 4;
    const int bf = tid >> 2, bd = (tid & 3) * 8;
    const bf16* f1es = f1p + (size_t)es * (DM * ESZ);

    f32x4 acc[2][4];
    #pragma unroll
    for (int mt = 0; mt < 2; ++mt)
        #pragma unroll
        for (int nt = 0; nt < 4; ++nt)
            acc[mt][nt] = (f32x4){0.f, 0.f, 0.f, 0.f};

    for (int k0 = 0; k0 < DM; k0 += 32) {
        #pragma unroll
        for (int p = 0; p < 4; ++p) {
            int grow = p * 32 + (tid >> 3);
            float4 v = *(const float4*)(x + (size_t)tokrow[p] * DM + k0 + c4);
            bf16x4 ob = {(bf16)v.x, (bf16)v.y, (bf16)v.z, (bf16)v.w};
            *(bf16x4*)(As + grow * 40 + c4) = ob;
        }
        {
            bf16x8 v = *(const bf16x8*)(f1es + bf * 1024 + k0 + bd);
            *(bf16x8*)(Bs + bf * 40 + bd) = v;
        }
        __syncthreads();
        bf16x8 av[2], bv[4];
        #pragma unroll
        for (int mt = 0; mt < 2; ++mt)
            av[mt] = *(const bf16x8*)(As + (w * 32 + mt * 16 + lr) * 40 + quad * 8);
        #pragma unroll
        for (int nt = 0; nt < 4; ++nt)
            bv[nt] = *(const bf16x8*)(Bs + (nt * 16 + lr) * 40 + quad * 8);
        #pragma unroll
        for (int mt = 0; mt < 2; ++mt)
            #pragma unroll
            for (int nt = 0; nt < 4; ++nt)
                acc[mt][nt] = __builtin_amdgcn_mfma_f32_16x16x32_bf16(
                    av[mt], bv[nt], acc[mt][nt], 0, 0, 0);
        __syncthreads();
    }
    bf16* innes = inner + (size_t)es * (NG * ESZ);
    #pragma unroll
    for (int mt = 0; mt < 2; ++mt)
        #pragma unroll
        for (int nt = 0; nt < 4; ++nt) {
            int f = nt * 16 + lr;
            float b = bias[es * 64 + f];
            #pragma unroll
            for (int r = 0; r < 4; ++r) {
                int grow = w * 32 + mt * 16 + quad * 4 + r;
                float v = acc[mt][nt][r] + b;
                v = v > 0.f ? v : 0.f;
                innes[(size_t)(g0 + grow) * 64 + f] = (bf16)v;
            }
        }
}

// ---------------- K3: FFN2 + un-permute scatter ----------------
// Unchanged (round-2 verified): LDS-staged A/B via global_load_lds width=16,
// double-buffered, counted vmcnt(2), source-side XOR swizzle, race-free accs
// scatter, nontemporal out stores.
__global__ __launch_bounds__(256) void k3_ffn2(const bf16* __restrict__ inner,
                                               const bf16* __restrict__ f2t,
                                               const unsigned* __restrict__ selp,
                                               float* __restrict__ out) {
    __shared__ float accs[512 * 32];                 // 64 KB
    __shared__ __align__(16) bf16 As[2][32 * 64];    // 8 KB (2 x 4 KB tiles)
    __shared__ __align__(16) bf16 Bs[2][32 * 64];    // 8 KB   -> 80 KB total, 2 blk/CU
    const int d0  = blockIdx.x * 32;
    const int g0  = blockIdx.y * 32;
    const int tid = threadIdx.x;
    const int w = tid >> 6, l = tid & 63, quad = l >> 4, lr = l & 15;
    const int mh = w >> 1, nh = w & 1;

    unsigned sp[4][8];
    #pragma unroll
    for (int r = 0; r < 4; ++r) {
        int gl = mh * 16 + quad * 4 + r;
        uint4 a = *(const uint4*)(selp + (size_t)(g0 + gl) * 8);
        uint4 b = *(const uint4*)(selp + (size_t)(g0 + gl) * 8 + 4);
        sp[r][0] = a.x; sp[r][1] = a.y; sp[r][2] = a.z; sp[r][3] = a.w;
        sp[r][4] = b.x; sp[r][5] = b.y; sp[r][6] = b.z; sp[r][7] = b.w;
    }

    const int srow = tid >> 3;
    const int scb  = ((tid & 7) * 16) ^ ((srow & 7) << 4);
    const bf16* srcA = inner + (size_t)(g0 + srow) * 64 + (scb >> 1);
    const bf16* srcB = f2t   + (size_t)(d0 + srow) * 64 + (scb >> 1);
    bf16* dA0 = &As[0][w * 512]; bf16* dA1 = &As[1][w * 512];
    bf16* dB0 = &Bs[0][w * 512]; bf16* dB1 = &Bs[1][w * 512];

    #pragma unroll
    for (int i = 0; i < 16; ++i)
        ((f32x4*)accs)[i * 256 + tid] = (f32x4){0.f, 0.f, 0.f, 0.f};

    gld_lds16(srcA, dA0);
    gld_lds16(srcB, dB0);
    __syncthreads();

    const int rowA = mh * 16 + lr, rowB = nh * 16 + lr;
    const int offA0 = rowA * 128 + ((quad * 16)      ^ ((rowA & 7) << 4));
    const int offA1 = rowA * 128 + ((quad * 16 + 64) ^ ((rowA & 7) << 4));
    const int offB0 = rowB * 128 + ((quad * 16)      ^ ((rowB & 7) << 4));
    const int offB1 = rowB * 128 + ((quad * 16 + 64) ^ ((rowB & 7) << 4));

    #pragma unroll
    for (int es = 0; es < 64; ++es) {
        const int cur = es & 1;
        if (es < 63) {
            if (cur == 0) { gld_lds16(srcA + (size_t)(es + 1) * 65536, dA1);
                            gld_lds16(srcB + (size_t)(es + 1) * 65536, dB1); }
            else          { gld_lds16(srcA + (size_t)(es + 1) * 65536, dA0);
                            gld_lds16(srcB + (size_t)(es + 1) * 65536, dB0); }
            asm volatile("s_waitcnt vmcnt(2)" ::: "memory");
        } else {
            asm volatile("s_waitcnt vmcnt(0)" ::: "memory");
        }
        asm volatile("s_barrier" ::: "memory");

        const char* a = (const char*)As[cur];
        const char* b = (const char*)Bs[cur];
        bf16x8 a0 = *(const bf16x8*)(a + offA0);
        bf16x8 a1 = *(const bf16x8*)(a + offA1);
        bf16x8 b0 = *(const bf16x8*)(b + offB0);
        bf16x8 b1 = *(const bf16x8*)(b + offB1);
        f32x4 z = {0.f, 0.f, 0.f, 0.f};
        z = __builtin_amdgcn_mfma_f32_16x16x32_bf16(a0, b0, z, 0, 0, 0);
        z = __builtin_amdgcn_mfma_f32_16x16x32_bf16(a1, b1, z, 0, 0, 0);

        const int dw = es >> 3, sh = (es & 7) * 4;
        #pragma unroll
        for (int r = 0; r < 4; ++r) {
            int t    = (sp[r][dw] >> sh) & 15;
            int gl   = mh * 16 + quad * 4 + r;
            int scol = (nh * 16 + lr) ^ ((t & 7) << 2);
            accs[(gl * 16 + t) * 32 + scol] += z[r];
        }
        asm volatile("s_barrier" ::: "memory");
    }
    __syncthreads();
    #pragma unroll
    for (int i = 0; i < 16; ++i) {
        int fi = i * 256 + tid;
        int row = fi >> 3, q = fi & 7;
        int scol4 = (q * 4) ^ ((row & 7) << 2);
        f32x4 v = *(f32x4*)(accs + row * 32 + scol4);
        __builtin_nontemporal_store(v, (f32x4*)(out + (size_t)(g0 * 16 + row) * DM + d0 + q * 4));
    }
}

extern "C" void kernel_launch(void* const* d_in, const int* in_sizes, int n_in,
                              void* d_out, int out_size, void* d_ws, size_t ws_size,
                              hipStream_t stream) {
    const float* x    = (const float*)d_in[0];
    const float* ctrl = (const float*)d_in[1];
    const float* f1   = (const float*)d_in[2];
    const float* f2   = (const float*)d_in[3];
    const float* bias = (const float*)d_in[4];
    float* out = (float*)d_out;

    char* ws = (char*)d_ws;
    bf16*     f1p   = (bf16*)(ws);                  // 8,388,608 B
    bf16*     f2t   = (bf16*)(ws + 8388608);        // 8,388,608 B
    bf16*     inner = (bf16*)(ws + 16777216);       // 8,388,608 B
    int*      sel   = (int*)(ws + 25165824);        //   262,144 B
    unsigned* selp  = (unsigned*)(ws + 25427968);   //    32,768 B

    // fused k0+k1: 2048 blocks (even = k1 group bg, odd = k0 tile), dynamic
    // LDS = max(k0 tile 64*65*4 = 16640 B, k1 12800 B)
    hipLaunchKernelGGL(k01_fused, dim3(2048), dim3(256), 16640, stream,
                       x, ctrl, f1, f2, f1p, f2t, sel, selp);
    hipLaunchKernelGGL(k2_ffn1,   dim3(8, 64),  dim3(256), 0, stream, x, f1p, bias, sel, inner);
    hipLaunchKernelGGL(k3_ffn2,   dim3(32, 32), dim3(256), 0, stream, inner, f2t, selp, out);
}

// Round 7
// 335.138 us; speedup vs baseline: 1.0290x; 1.0290x over previous
//
#include <hip/hip_runtime.h>

// BatchSplitFF: DM=1024, NE=16, ES=4 (NES=64 expert pairs), ESZ=64,
// BATCH*SEQ = 8*2048 tokens -> 1024 groups of 16 tokens.
#define DM   1024
#define NES  64
#define ESZ  64
#define NG   1024
#define TOK  16

typedef __bf16 bf16;
typedef __bf16 bf16x4 __attribute__((ext_vector_type(4)));
typedef __bf16 bf16x8 __attribute__((ext_vector_type(8)));
typedef float  f32x4  __attribute__((ext_vector_type(4)));

// async global->LDS, 16B per lane, LDS dest = wave-uniform base + lane*16
__device__ __forceinline__ void gld_lds16(const bf16* g, bf16* s) {
    __builtin_amdgcn_global_load_lds(
        (const __attribute__((address_space(1))) void*)g,
        (__attribute__((address_space(3))) void*)s, 16, 0, 0);
}

// ---------------- K0: transpose weights to bf16, MFMA-friendly layouts ----
// (verbatim round-2 passing version; ~17 us. Fusion with k1 (round 6) gave
// ZERO overlap and poisoned L2 -> reverted to standalone.)
__global__ __launch_bounds__(256) void k0_transpose(const float* __restrict__ f1,
                                                    const float* __restrict__ f2,
                                                    bf16* __restrict__ f1p,
                                                    bf16* __restrict__ f2t) {
    __shared__ float tile[64 * 65];
    const int es = blockIdx.y, d0 = blockIdx.x * 64, tid = threadIdx.x;
    #pragma unroll
    for (int i = 0; i < 4; ++i) {
        int idx = i * 256 + tid; int r = idx >> 4, c4 = (idx & 15) * 4;
        float4 v = *(const float4*)(f1 + (size_t)(d0 + r) * 4096 + es * 64 + c4);
        tile[r * 65 + c4] = v.x; tile[r * 65 + c4 + 1] = v.y;
        tile[r * 65 + c4 + 2] = v.z; tile[r * 65 + c4 + 3] = v.w;
    }
    __syncthreads();
    #pragma unroll
    for (int i = 0; i < 2; ++i) {
        int idx = i * 256 + tid; int f = idx >> 3, dl0 = (idx & 7) * 8;
        bf16x8 o;
        #pragma unroll
        for (int j = 0; j < 8; ++j) o[j] = (bf16)tile[(dl0 + j) * 65 + f];
        *(bf16x8*)(f1p + (size_t)es * 65536 + f * 1024 + d0 + dl0) = o;
    }
    __syncthreads();
    #pragma unroll
    for (int i = 0; i < 4; ++i) {
        int idx = i * 256 + tid; int r = idx >> 4, c4 = (idx & 15) * 4;
        float4 v = *(const float4*)(f2 + (size_t)es * 65536 + r * 1024 + d0 + c4);
        tile[r * 65 + c4] = v.x; tile[r * 65 + c4 + 1] = v.y;
        tile[r * 65 + c4 + 2] = v.z; tile[r * 65 + c4 + 3] = v.w;
    }
    __syncthreads();
    #pragma unroll
    for (int i = 0; i < 2; ++i) {
        int idx = i * 256 + tid; int dl = idx >> 3, f0 = (idx & 7) * 8;
        bf16x8 o;
        #pragma unroll
        for (int j = 0; j < 8; ++j) o[j] = (bf16)tile[(f0 + j) * 65 + dl];
        *(bf16x8*)(f2t + (size_t)es * 65536 + (size_t)(d0 + dl) * 64 + f0) = o;
    }
}

// ---------------- K1: fp32 logits + argmax + sel nibble-pack ----------------
// Round-7 structure: NO LDS in the hot loop. The round-2 kernel's x reads
// were wave-UNIFORM ds_read_b128 broadcasts (address depends only on the
// wave id) -- 16 waves/CU x 1024 instrs x ~12 cyc on the single per-CU LDS
// pipe = ~82 us, the measured bottleneck (round-5's 3x LDS-instr variant ran
// 1.42x slower, same model). x rows are now loaded DIRECTLY from global with
// wave-uniform float4 loads (readfirstlane'd row base -> scalarizable; each
// row is read exactly once by exactly one wave, L1-friendly 16B/64B-line
// locality). LDS pipe goes idle; no staging barriers remain.
// The per-(t,es) fmac chain is VERBATIM (single fmac per term, d strictly
// ascending, same source order, no fast-math) -> BIT-IDENTICAL logits.
__global__ __launch_bounds__(256) void k1_logits(const float* __restrict__ x,
                                                 const float* __restrict__ ctrl,
                                                 int* __restrict__ sel,
                                                 unsigned* __restrict__ selp) {
    __shared__ float sl[TOK * NES];   // 4 KB
    __shared__ int   st[NES];
    const int bg  = blockIdx.x;
    const int tid = threadIdx.x;
    const int es  = tid & 63;
    const int tq  = tid >> 6;            // wave 0..3 -> rows tq*4 .. tq*4+3
    const float* xg = x + (size_t)bg * (TOK * DM);
    const float* cp = ctrl + es;

    // wave-uniform row bases (readfirstlane: guarantee the compiler sees the
    // addresses as uniform -> scalar/uniform loads, zero LDS traffic)
    const int tqu = __builtin_amdgcn_readfirstlane(tq);
    const float* xr0 = xg + (size_t)(tqu * 4 + 0) * DM;
    const float* xr1 = xg + (size_t)(tqu * 4 + 1) * DM;
    const float* xr2 = xg + (size_t)(tqu * 4 + 2) * DM;
    const float* xr3 = xg + (size_t)(tqu * 4 + 3) * DM;

    float acc[4] = {0.f, 0.f, 0.f, 0.f};
    #pragma unroll 8
    for (int d = 0; d < DM; d += 4) {
        float4 v0 = *(const float4*)(xr0 + d);
        float4 v1 = *(const float4*)(xr1 + d);
        float4 v2 = *(const float4*)(xr2 + d);
        float4 v3 = *(const float4*)(xr3 + d);
        float c0 = cp[(size_t)(d + 0) * 64];
        float c1 = cp[(size_t)(d + 1) * 64];
        float c2 = cp[(size_t)(d + 2) * 64];
        float c3 = cp[(size_t)(d + 3) * 64];
        acc[0] += v0.x * c0; acc[1] += v1.x * c0;
        acc[2] += v2.x * c0; acc[3] += v3.x * c0;
        acc[0] += v0.y * c1; acc[1] += v1.y * c1;
        acc[2] += v2.y * c1; acc[3] += v3.y * c1;
        acc[0] += v0.z * c2; acc[1] += v1.z * c2;
        acc[2] += v2.z * c2; acc[3] += v3.z * c2;
        acc[0] += v0.w * c3; acc[1] += v1.w * c3;
        acc[2] += v2.w * c3; acc[3] += v3.w * c3;
    }
    #pragma unroll
    for (int i = 0; i < 4; ++i) {
        int t = tq * 4 + i;
        sl[t * NES + es] = acc[i] + (float)t * (1e-6f / 15.f);
    }
    __syncthreads();
    if (tid < NES) {
        float best = -1e30f; int bi = 0;
        #pragma unroll
        for (int t = 0; t < TOK; ++t) {
            float v = sl[t * NES + tid];
            if (v >= best) { best = v; bi = t; }   // >= : later t wins ties
        }
        sel[bg * NES + tid] = bi;
        st[tid] = bi;
    }
    __syncthreads();
    if (tid < 8) {   // pack 8 es per dword, 4-bit each
        unsigned p = 0;
        #pragma unroll
        for (int k = 0; k < 8; ++k) p |= (unsigned)st[tid * 8 + k] << (4 * k);
        selp[bg * 8 + tid] = p;
    }
}

// ---------------- K2: FFN1 (gather + GEMM + bias + relu) ----------------
// Exact round-2 version (next optimization target: ~130 us, 2 blocks/CU).
__global__ __launch_bounds__(256) void k2_ffn1(const float* __restrict__ x,
                                               const bf16* __restrict__ f1p,
                                               const float* __restrict__ bias,
                                               const int* __restrict__ sel,
                                               bf16* __restrict__ inner) {
    __shared__ int  sel_s[128];
    __shared__ __align__(16) bf16 As[128 * 40];
    __shared__ __align__(16) bf16 Bs[64 * 40];
    const int es  = blockIdx.y;
    const int g0  = blockIdx.x * 128;
    const int tid = threadIdx.x;
    if (tid < 128) sel_s[tid] = sel[(g0 + tid) * 64 + es];
    __syncthreads();

    const int w = tid >> 6, l = tid & 63, quad = l >> 4, lr = l & 15;
    int tokrow[4];
    #pragma unroll
    for (int p = 0; p < 4; ++p) {
        int grow = p * 32 + (tid >> 3);
        tokrow[p] = (g0 + grow) * 16 + sel_s[grow];
    }
    const int c4 = (tid & 7) * 4;
    const int bf = tid >> 2, bd = (tid & 3) * 8;
    const bf16* f1es = f1p + (size_t)es * (DM * ESZ);

    f32x4 acc[2][4];
    #pragma unroll
    for (int mt = 0; mt < 2; ++mt)
        #pragma unroll
        for (int nt = 0; nt < 4; ++nt)
            acc[mt][nt] = (f32x4){0.f, 0.f, 0.f, 0.f};

    for (int k0 = 0; k0 < DM; k0 += 32) {
        #pragma unroll
        for (int p = 0; p < 4; ++p) {
            int grow = p * 32 + (tid >> 3);
            float4 v = *(const float4*)(x + (size_t)tokrow[p] * DM + k0 + c4);
            bf16x4 ob = {(bf16)v.x, (bf16)v.y, (bf16)v.z, (bf16)v.w};
            *(bf16x4*)(As + grow * 40 + c4) = ob;
        }
        {
            bf16x8 v = *(const bf16x8*)(f1es + bf * 1024 + k0 + bd);
            *(bf16x8*)(Bs + bf * 40 + bd) = v;
        }
        __syncthreads();
        bf16x8 av[2], bv[4];
        #pragma unroll
        for (int mt = 0; mt < 2; ++mt)
            av[mt] = *(const bf16x8*)(As + (w * 32 + mt * 16 + lr) * 40 + quad * 8);
        #pragma unroll
        for (int nt = 0; nt < 4; ++nt)
            bv[nt] = *(const bf16x8*)(Bs + (nt * 16 + lr) * 40 + quad * 8);
        #pragma unroll
        for (int mt = 0; mt < 2; ++mt)
            #pragma unroll
            for (int nt = 0; nt < 4; ++nt)
                acc[mt][nt] = __builtin_amdgcn_mfma_f32_16x16x32_bf16(
                    av[mt], bv[nt], acc[mt][nt], 0, 0, 0);
        __syncthreads();
    }
    bf16* innes = inner + (size_t)es * (NG * ESZ);
    #pragma unroll
    for (int mt = 0; mt < 2; ++mt)
        #pragma unroll
        for (int nt = 0; nt < 4; ++nt) {
            int f = nt * 16 + lr;
            float b = bias[es * 64 + f];
            #pragma unroll
            for (int r = 0; r < 4; ++r) {
                int grow = w * 32 + mt * 16 + quad * 4 + r;
                float v = acc[mt][nt][r] + b;
                v = v > 0.f ? v : 0.f;
                innes[(size_t)(g0 + grow) * 64 + f] = (bf16)v;
            }
        }
}

// ---------------- K3: FFN2 + un-permute scatter ----------------
// Unchanged (round-2 verified): LDS-staged A/B via global_load_lds width=16,
// double-buffered, counted vmcnt(2), source-side XOR swizzle, race-free accs
// scatter, nontemporal out stores.
__global__ __launch_bounds__(256) void k3_ffn2(const bf16* __restrict__ inner,
                                               const bf16* __restrict__ f2t,
                                               const unsigned* __restrict__ selp,
                                               float* __restrict__ out) {
    __shared__ float accs[512 * 32];                 // 64 KB
    __shared__ __align__(16) bf16 As[2][32 * 64];    // 8 KB (2 x 4 KB tiles)
    __shared__ __align__(16) bf16 Bs[2][32 * 64];    // 8 KB   -> 80 KB total, 2 blk/CU
    const int d0  = blockIdx.x * 32;
    const int g0  = blockIdx.y * 32;
    const int tid = threadIdx.x;
    const int w = tid >> 6, l = tid & 63, quad = l >> 4, lr = l & 15;
    const int mh = w >> 1, nh = w & 1;

    unsigned sp[4][8];
    #pragma unroll
    for (int r = 0; r < 4; ++r) {
        int gl = mh * 16 + quad * 4 + r;
        uint4 a = *(const uint4*)(selp + (size_t)(g0 + gl) * 8);
        uint4 b = *(const uint4*)(selp + (size_t)(g0 + gl) * 8 + 4);
        sp[r][0] = a.x; sp[r][1] = a.y; sp[r][2] = a.z; sp[r][3] = a.w;
        sp[r][4] = b.x; sp[r][5] = b.y; sp[r][6] = b.z; sp[r][7] = b.w;
    }

    const int srow = tid >> 3;
    const int scb  = ((tid & 7) * 16) ^ ((srow & 7) << 4);
    const bf16* srcA = inner + (size_t)(g0 + srow) * 64 + (scb >> 1);
    const bf16* srcB = f2t   + (size_t)(d0 + srow) * 64 + (scb >> 1);
    bf16* dA0 = &As[0][w * 512]; bf16* dA1 = &As[1][w * 512];
    bf16* dB0 = &Bs[0][w * 512]; bf16* dB1 = &Bs[1][w * 512];

    #pragma unroll
    for (int i = 0; i < 16; ++i)
        ((f32x4*)accs)[i * 256 + tid] = (f32x4){0.f, 0.f, 0.f, 0.f};

    gld_lds16(srcA, dA0);
    gld_lds16(srcB, dB0);
    __syncthreads();

    const int rowA = mh * 16 + lr, rowB = nh * 16 + lr;
    const int offA0 = rowA * 128 + ((quad * 16)      ^ ((rowA & 7) << 4));
    const int offA1 = rowA * 128 + ((quad * 16 + 64) ^ ((rowA & 7) << 4));
    const int offB0 = rowB * 128 + ((quad * 16)      ^ ((rowB & 7) << 4));
    const int offB1 = rowB * 128 + ((quad * 16 + 64) ^ ((rowB & 7) << 4));

    #pragma unroll
    for (int es = 0; es < 64; ++es) {
        const int cur = es & 1;
        if (es < 63) {
            if (cur == 0) { gld_lds16(srcA + (size_t)(es + 1) * 65536, dA1);
                            gld_lds16(srcB + (size_t)(es + 1) * 65536, dB1); }
            else          { gld_lds16(srcA + (size_t)(es + 1) * 65536, dA0);
                            gld_lds16(srcB + (size_t)(es + 1) * 65536, dB0); }
            asm volatile("s_waitcnt vmcnt(2)" ::: "memory");
        } else {
            asm volatile("s_waitcnt vmcnt(0)" ::: "memory");
        }
        asm volatile("s_barrier" ::: "memory");

        const char* a = (const char*)As[cur];
        const char* b = (const char*)Bs[cur];
        bf16x8 a0 = *(const bf16x8*)(a + offA0);
        bf16x8 a1 = *(const bf16x8*)(a + offA1);
        bf16x8 b0 = *(const bf16x8*)(b + offB0);
        bf16x8 b1 = *(const bf16x8*)(b + offB1);
        f32x4 z = {0.f, 0.f, 0.f, 0.f};
        z = __builtin_amdgcn_mfma_f32_16x16x32_bf16(a0, b0, z, 0, 0, 0);
        z = __builtin_amdgcn_mfma_f32_16x16x32_bf16(a1, b1, z, 0, 0, 0);

        const int dw = es >> 3, sh = (es & 7) * 4;
        #pragma unroll
        for (int r = 0; r < 4; ++r) {
            int t    = (sp[r][dw] >> sh) & 15;
            int gl   = mh * 16 + quad * 4 + r;
            int scol = (nh * 16 + lr) ^ ((t & 7) << 2);
            accs[(gl * 16 + t) * 32 + scol] += z[r];
        }
        asm volatile("s_barrier" ::: "memory");
    }
    __syncthreads();
    #pragma unroll
    for (int i = 0; i < 16; ++i) {
        int fi = i * 256 + tid;
        int row = fi >> 3, q = fi & 7;
        int scol4 = (q * 4) ^ ((row & 7) << 2);
        f32x4 v = *(f32x4*)(accs + row * 32 + scol4);
        __builtin_nontemporal_store(v, (f32x4*)(out + (size_t)(g0 * 16 + row) * DM + d0 + q * 4));
    }
}

extern "C" void kernel_launch(void* const* d_in, const int* in_sizes, int n_in,
                              void* d_out, int out_size, void* d_ws, size_t ws_size,
                              hipStream_t stream) {
    const float* x    = (const float*)d_in[0];
    const float* ctrl = (const float*)d_in[1];
    const float* f1   = (const float*)d_in[2];
    const float* f2   = (const float*)d_in[3];
    const float* bias = (const float*)d_in[4];
    float* out = (float*)d_out;

    char* ws = (char*)d_ws;
    bf16*     f1p   = (bf16*)(ws);                  // 8,388,608 B
    bf16*     f2t   = (bf16*)(ws + 8388608);        // 8,388,608 B
    bf16*     inner = (bf16*)(ws + 16777216);       // 8,388,608 B
    int*      sel   = (int*)(ws + 25165824);        //   262,144 B
    unsigned* selp  = (unsigned*)(ws + 25427968);   //    32,768 B

    hipLaunchKernelGGL(k0_transpose, dim3(16, 64), dim3(256), 0, stream, f1, f2, f1p, f2t);
    hipLaunchKernelGGL(k1_logits,    dim3(1024),   dim3(256), 0, stream, x, ctrl, sel, selp);
    hipLaunchKernelGGL(k2_ffn1,      dim3(8, 64),  dim3(256), 0, stream, x, f1p, bias, sel, inner);
    hipLaunchKernelGGL(k3_ffn2,      dim3(32, 32), dim3(256), 0, stream, inner, f2t, selp, out);
}

// Round 8
// 303.446 us; speedup vs baseline: 1.1364x; 1.1044x over previous
//
#include <hip/hip_runtime.h>

// BatchSplitFF: DM=1024, NE=16, ES=4 (NES=64 expert pairs), ESZ=64,
// BATCH*SEQ = 8*2048 tokens -> 1024 groups of 16 tokens.
#define DM   1024
#define NES  64
#define ESZ  64
#define NG   1024
#define TOK  16

typedef __bf16 bf16;
typedef __bf16 bf16x4 __attribute__((ext_vector_type(4)));
typedef __bf16 bf16x8 __attribute__((ext_vector_type(8)));
typedef float  f32x4  __attribute__((ext_vector_type(4)));

// async global->LDS, 16B per lane, LDS dest = wave-uniform base + lane*16
__device__ __forceinline__ void gld_lds16(const bf16* g, bf16* s) {
    __builtin_amdgcn_global_load_lds(
        (const __attribute__((address_space(1))) void*)g,
        (__attribute__((address_space(3))) void*)s, 16, 0, 0);
}

// ---------------- K0: transpose weights to bf16, MFMA-friendly layouts ----
// (verbatim round-2 passing version, ~17 us)
__global__ __launch_bounds__(256) void k0_transpose(const float* __restrict__ f1,
                                                    const float* __restrict__ f2,
                                                    bf16* __restrict__ f1p,
                                                    bf16* __restrict__ f2t) {
    __shared__ float tile[64 * 65];
    const int es = blockIdx.y, d0 = blockIdx.x * 64, tid = threadIdx.x;
    #pragma unroll
    for (int i = 0; i < 4; ++i) {
        int idx = i * 256 + tid; int r = idx >> 4, c4 = (idx & 15) * 4;
        float4 v = *(const float4*)(f1 + (size_t)(d0 + r) * 4096 + es * 64 + c4);
        tile[r * 65 + c4] = v.x; tile[r * 65 + c4 + 1] = v.y;
        tile[r * 65 + c4 + 2] = v.z; tile[r * 65 + c4 + 3] = v.w;
    }
    __syncthreads();
    #pragma unroll
    for (int i = 0; i < 2; ++i) {
        int idx = i * 256 + tid; int f = idx >> 3, dl0 = (idx & 7) * 8;
        bf16x8 o;
        #pragma unroll
        for (int j = 0; j < 8; ++j) o[j] = (bf16)tile[(dl0 + j) * 65 + f];
        *(bf16x8*)(f1p + (size_t)es * 65536 + f * 1024 + d0 + dl0) = o;
    }
    __syncthreads();
    #pragma unroll
    for (int i = 0; i < 4; ++i) {
        int idx = i * 256 + tid; int r = idx >> 4, c4 = (idx & 15) * 4;
        float4 v = *(const float4*)(f2 + (size_t)es * 65536 + r * 1024 + d0 + c4);
        tile[r * 65 + c4] = v.x; tile[r * 65 + c4 + 1] = v.y;
        tile[r * 65 + c4 + 2] = v.z; tile[r * 65 + c4 + 3] = v.w;
    }
    __syncthreads();
    #pragma unroll
    for (int i = 0; i < 2; ++i) {
        int idx = i * 256 + tid; int dl = idx >> 3, f0 = (idx & 7) * 8;
        bf16x8 o;
        #pragma unroll
        for (int j = 0; j < 8; ++j) o[j] = (bf16)tile[(f0 + j) * 65 + dl];
        *(bf16x8*)(f2t + (size_t)es * 65536 + (size_t)(d0 + dl) * 64 + f0) = o;
    }
}

// ---------------- K1: fp32 logits + argmax + sel nibble-pack ----------------
// FROZEN at the round-2 structure (91.6 us, best of 4 measured variants).
// Model: its time is the serialized SUM of fmac (13.7us) + LDS-broadcast
// (~29us) + ctrl-VMEM (~30us) + barriers; every single-pipe swap regressed:
// LDS-ctrl staging 130us (LDS-pipe overload), k0-fusion 149us (L2 poison),
// scalarized x 115us (K$ thrash, 2x FETCH). Do not touch without a theory
// that reduces TOTAL instruction count across pipes.
// Per-(t,es) chain: single fmac per term, d strictly ascending ->
// BIT-IDENTICAL logits to all passing rounds.
__global__ __launch_bounds__(256) void k1_logits(const float* __restrict__ x,
                                                 const float* __restrict__ ctrl,
                                                 int* __restrict__ sel,
                                                 unsigned* __restrict__ selp) {
    __shared__ __align__(16) float xs[TOK * 132];   // row stride 132 (528B, 16B-mult)
    __shared__ float sl[TOK * NES];
    __shared__ int   st[NES];
    const int bg  = blockIdx.x;
    const int tid = threadIdx.x;
    const int es  = tid & 63;
    const int tq  = tid >> 6;            // wave 0..3 -> rows tq*4 .. tq*4+3
    const float* xg = x + (size_t)bg * (TOK * DM);
    const float* cp = ctrl + es;
    float acc[4] = {0.f, 0.f, 0.f, 0.f};
    for (int d0 = 0; d0 < DM; d0 += 128) {
        __syncthreads();
        #pragma unroll
        for (int c = 0; c < 2; ++c) {    // stage 16 x 128 chunk (coalesced)
            int idx = tid + c * 256;
            int tr  = idx >> 5;
            int c4  = (idx & 31) * 4;
            float4 v = *(const float4*)(xg + tr * DM + d0 + c4);
            *(float4*)(xs + tr * 132 + c4) = v;
        }
        __syncthreads();
        #pragma unroll 2
        for (int dl4 = 0; dl4 < 128; dl4 += 4) {
            float4 v0 = *(const float4*)(xs + (tq * 4 + 0) * 132 + dl4);
            float4 v1 = *(const float4*)(xs + (tq * 4 + 1) * 132 + dl4);
            float4 v2 = *(const float4*)(xs + (tq * 4 + 2) * 132 + dl4);
            float4 v3 = *(const float4*)(xs + (tq * 4 + 3) * 132 + dl4);
            float c0 = cp[(size_t)(d0 + dl4 + 0) * 64];
            float c1 = cp[(size_t)(d0 + dl4 + 1) * 64];
            float c2 = cp[(size_t)(d0 + dl4 + 2) * 64];
            float c3 = cp[(size_t)(d0 + dl4 + 3) * 64];
            acc[0] += v0.x * c0; acc[1] += v1.x * c0;
            acc[2] += v2.x * c0; acc[3] += v3.x * c0;
            acc[0] += v0.y * c1; acc[1] += v1.y * c1;
            acc[2] += v2.y * c1; acc[3] += v3.y * c1;
            acc[0] += v0.z * c2; acc[1] += v1.z * c2;
            acc[2] += v2.z * c2; acc[3] += v3.z * c2;
            acc[0] += v0.w * c3; acc[1] += v1.w * c3;
            acc[2] += v2.w * c3; acc[3] += v3.w * c3;
        }
    }
    #pragma unroll
    for (int i = 0; i < 4; ++i) {
        int t = tq * 4 + i;
        sl[t * NES + es] = acc[i] + (float)t * (1e-6f / 15.f);
    }
    __syncthreads();
    if (tid < NES) {
        float best = -1e30f; int bi = 0;
        #pragma unroll
        for (int t = 0; t < TOK; ++t) {
            float v = sl[t * NES + tid];
            if (v >= best) { best = v; bi = t; }   // >= : later t wins ties
        }
        sel[bg * NES + tid] = bi;
        st[tid] = bi;
    }
    __syncthreads();
    if (tid < 8) {   // pack 8 es per dword, 4-bit each
        unsigned p = 0;
        #pragma unroll
        for (int k = 0; k < 8; ++k) p |= (unsigned)st[tid * 8 + k] << (4 * k);
        selp[bg * 8 + tid] = p;
    }
}

// ---------------- K2: FFN1 (gather + GEMM + bias + relu) ----------------
// Round-8 structure: round-2 MFMA/tile/output kept EXACTLY (bit-identical
// inner), but the per-k-step gather+B loads are now a 2-DEEP register
// pipeline: loads for step k+64 / k+96 are issued right after the staging
// barrier and consumed two barriers later, so each load has ~2 MFMA-phases
// (~600-800 cyc) in flight to cover LLC gather latency (~900 cyc). This is
// the same medicine that took k3 from 125 -> ~85 us in round 2; k2's 32
// serially-latency-exposed k-steps were ~40 us of its ~85.
__global__ __launch_bounds__(256) void k2_ffn1(const float* __restrict__ x,
                                               const bf16* __restrict__ f1p,
                                               const float* __restrict__ bias,
                                               const int* __restrict__ sel,
                                               bf16* __restrict__ inner) {
    __shared__ int  sel_s[128];
    __shared__ __align__(16) bf16 As[128 * 40];
    __shared__ __align__(16) bf16 Bs[64 * 40];
    const int es  = blockIdx.y;
    const int g0  = blockIdx.x * 128;
    const int tid = threadIdx.x;
    if (tid < 128) sel_s[tid] = sel[(g0 + tid) * 64 + es];
    __syncthreads();

    const int w = tid >> 6, l = tid & 63, quad = l >> 4, lr = l & 15;
    int tokrow[4];
    #pragma unroll
    for (int p = 0; p < 4; ++p) {
        int grow = p * 32 + (tid >> 3);
        tokrow[p] = (g0 + grow) * 16 + sel_s[grow];
    }
    const int c4 = (tid & 7) * 4;
    const int bf = tid >> 2, bd = (tid & 3) * 8;
    const bf16* f1es = f1p + (size_t)es * (DM * ESZ);

    f32x4 acc[2][4];
    #pragma unroll
    for (int mt = 0; mt < 2; ++mt)
        #pragma unroll
        for (int nt = 0; nt < 4; ++nt)
            acc[mt][nt] = (f32x4){0.f, 0.f, 0.f, 0.f};

    // 2-deep register pipeline: slot A = k-step k0, slot B = k0+32
    float4 rA0, rA1, rA2, rA3, rB0, rB1, rB2, rB3;
    bf16x8 rbA, rbB;
    rA0 = *(const float4*)(x + (size_t)tokrow[0] * DM + 0 + c4);
    rA1 = *(const float4*)(x + (size_t)tokrow[1] * DM + 0 + c4);
    rA2 = *(const float4*)(x + (size_t)tokrow[2] * DM + 0 + c4);
    rA3 = *(const float4*)(x + (size_t)tokrow[3] * DM + 0 + c4);
    rbA = *(const bf16x8*)(f1es + bf * 1024 + 0 + bd);
    rB0 = *(const float4*)(x + (size_t)tokrow[0] * DM + 32 + c4);
    rB1 = *(const float4*)(x + (size_t)tokrow[1] * DM + 32 + c4);
    rB2 = *(const float4*)(x + (size_t)tokrow[2] * DM + 32 + c4);
    rB3 = *(const float4*)(x + (size_t)tokrow[3] * DM + 32 + c4);
    rbB = *(const bf16x8*)(f1es + bf * 1024 + 32 + bd);

    for (int k0 = 0; k0 < DM; k0 += 64) {
        // ---- step A (k = k0), staged from slot-A regs ----
        {
            bf16x4 o0 = {(bf16)rA0.x, (bf16)rA0.y, (bf16)rA0.z, (bf16)rA0.w};
            bf16x4 o1 = {(bf16)rA1.x, (bf16)rA1.y, (bf16)rA1.z, (bf16)rA1.w};
            bf16x4 o2 = {(bf16)rA2.x, (bf16)rA2.y, (bf16)rA2.z, (bf16)rA2.w};
            bf16x4 o3 = {(bf16)rA3.x, (bf16)rA3.y, (bf16)rA3.z, (bf16)rA3.w};
            *(bf16x4*)(As + (0 * 32 + (tid >> 3)) * 40 + c4) = o0;
            *(bf16x4*)(As + (1 * 32 + (tid >> 3)) * 40 + c4) = o1;
            *(bf16x4*)(As + (2 * 32 + (tid >> 3)) * 40 + c4) = o2;
            *(bf16x4*)(As + (3 * 32 + (tid >> 3)) * 40 + c4) = o3;
            *(bf16x8*)(Bs + bf * 40 + bd) = rbA;
        }
        __syncthreads();
        if (k0 + 64 < DM) {   // refill slot A from k0+64 (2 phases of cover)
            rA0 = *(const float4*)(x + (size_t)tokrow[0] * DM + k0 + 64 + c4);
            rA1 = *(const float4*)(x + (size_t)tokrow[1] * DM + k0 + 64 + c4);
            rA2 = *(const float4*)(x + (size_t)tokrow[2] * DM + k0 + 64 + c4);
            rA3 = *(const float4*)(x + (size_t)tokrow[3] * DM + k0 + 64 + c4);
            rbA = *(const bf16x8*)(f1es + bf * 1024 + k0 + 64 + bd);
        }
        {
            bf16x8 av[2], bv[4];
            #pragma unroll
            for (int mt = 0; mt < 2; ++mt)
                av[mt] = *(const bf16x8*)(As + (w * 32 + mt * 16 + lr) * 40 + quad * 8);
            #pragma unroll
            for (int nt = 0; nt < 4; ++nt)
                bv[nt] = *(const bf16x8*)(Bs + (nt * 16 + lr) * 40 + quad * 8);
            #pragma unroll
            for (int mt = 0; mt < 2; ++mt)
                #pragma unroll
                for (int nt = 0; nt < 4; ++nt)
                    acc[mt][nt] = __builtin_amdgcn_mfma_f32_16x16x32_bf16(
                        av[mt], bv[nt], acc[mt][nt], 0, 0, 0);
        }
        __syncthreads();
        // ---- step B (k = k0+32), staged from slot-B regs ----
        {
            bf16x4 o0 = {(bf16)rB0.x, (bf16)rB0.y, (bf16)rB0.z, (bf16)rB0.w};
            bf16x4 o1 = {(bf16)rB1.x, (bf16)rB1.y, (bf16)rB1.z, (bf16)rB1.w};
            bf16x4 o2 = {(bf16)rB2.x, (bf16)rB2.y, (bf16)rB2.z, (bf16)rB2.w};
            bf16x4 o3 = {(bf16)rB3.x, (bf16)rB3.y, (bf16)rB3.z, (bf16)rB3.w};
            *(bf16x4*)(As + (0 * 32 + (tid >> 3)) * 40 + c4) = o0;
            *(bf16x4*)(As + (1 * 32 + (tid >> 3)) * 40 + c4) = o1;
            *(bf16x4*)(As + (2 * 32 + (tid >> 3)) * 40 + c4) = o2;
            *(bf16x4*)(As + (3 * 32 + (tid >> 3)) * 40 + c4) = o3;
            *(bf16x8*)(Bs + bf * 40 + bd) = rbB;
        }
        __syncthreads();
        if (k0 + 96 < DM) {   // refill slot B from k0+96
            rB0 = *(const float4*)(x + (size_t)tokrow[0] * DM + k0 + 96 + c4);
            rB1 = *(const float4*)(x + (size_t)tokrow[1] * DM + k0 + 96 + c4);
            rB2 = *(const float4*)(x + (size_t)tokrow[2] * DM + k0 + 96 + c4);
            rB3 = *(const float4*)(x + (size_t)tokrow[3] * DM + k0 + 96 + c4);
            rbB = *(const bf16x8*)(f1es + bf * 1024 + k0 + 96 + bd);
        }
        {
            bf16x8 av[2], bv[4];
            #pragma unroll
            for (int mt = 0; mt < 2; ++mt)
                av[mt] = *(const bf16x8*)(As + (w * 32 + mt * 16 + lr) * 40 + quad * 8);
            #pragma unroll
            for (int nt = 0; nt < 4; ++nt)
                bv[nt] = *(const bf16x8*)(Bs + (nt * 16 + lr) * 40 + quad * 8);
            #pragma unroll
            for (int mt = 0; mt < 2; ++mt)
                #pragma unroll
                for (int nt = 0; nt < 4; ++nt)
                    acc[mt][nt] = __builtin_amdgcn_mfma_f32_16x16x32_bf16(
                        av[mt], bv[nt], acc[mt][nt], 0, 0, 0);
        }
        __syncthreads();
    }
    bf16* innes = inner + (size_t)es * (NG * ESZ);
    #pragma unroll
    for (int mt = 0; mt < 2; ++mt)
        #pragma unroll
        for (int nt = 0; nt < 4; ++nt) {
            int f = nt * 16 + lr;
            float b = bias[es * 64 + f];
            #pragma unroll
            for (int r = 0; r < 4; ++r) {
                int grow = w * 32 + mt * 16 + quad * 4 + r;
                float v = acc[mt][nt][r] + b;
                v = v > 0.f ? v : 0.f;
                innes[(size_t)(g0 + grow) * 64 + f] = (bf16)v;
            }
        }
}

// ---------------- K3: FFN2 + un-permute scatter ----------------
// Unchanged (round-2 verified): LDS-staged A/B via global_load_lds width=16,
// double-buffered, counted vmcnt(2), source-side XOR swizzle, race-free accs
// scatter, nontemporal out stores.
__global__ __launch_bounds__(256) void k3_ffn2(const bf16* __restrict__ inner,
                                               const bf16* __restrict__ f2t,
                                               const unsigned* __restrict__ selp,
                                               float* __restrict__ out) {
    __shared__ float accs[512 * 32];                 // 64 KB
    __shared__ __align__(16) bf16 As[2][32 * 64];    // 8 KB (2 x 4 KB tiles)
    __shared__ __align__(16) bf16 Bs[2][32 * 64];    // 8 KB   -> 80 KB total, 2 blk/CU
    const int d0  = blockIdx.x * 32;
    const int g0  = blockIdx.y * 32;
    const int tid = threadIdx.x;
    const int w = tid >> 6, l = tid & 63, quad = l >> 4, lr = l & 15;
    const int mh = w >> 1, nh = w & 1;

    unsigned sp[4][8];
    #pragma unroll
    for (int r = 0; r < 4; ++r) {
        int gl = mh * 16 + quad * 4 + r;
        uint4 a = *(const uint4*)(selp + (size_t)(g0 + gl) * 8);
        uint4 b = *(const uint4*)(selp + (size_t)(g0 + gl) * 8 + 4);
        sp[r][0] = a.x; sp[r][1] = a.y; sp[r][2] = a.z; sp[r][3] = a.w;
        sp[r][4] = b.x; sp[r][5] = b.y; sp[r][6] = b.z; sp[r][7] = b.w;
    }

    const int srow = tid >> 3;
    const int scb  = ((tid & 7) * 16) ^ ((srow & 7) << 4);
    const bf16* srcA = inner + (size_t)(g0 + srow) * 64 + (scb >> 1);
    const bf16* srcB = f2t   + (size_t)(d0 + srow) * 64 + (scb >> 1);
    bf16* dA0 = &As[0][w * 512]; bf16* dA1 = &As[1][w * 512];
    bf16* dB0 = &Bs[0][w * 512]; bf16* dB1 = &Bs[1][w * 512];

    #pragma unroll
    for (int i = 0; i < 16; ++i)
        ((f32x4*)accs)[i * 256 + tid] = (f32x4){0.f, 0.f, 0.f, 0.f};

    gld_lds16(srcA, dA0);
    gld_lds16(srcB, dB0);
    __syncthreads();

    const int rowA = mh * 16 + lr, rowB = nh * 16 + lr;
    const int offA0 = rowA * 128 + ((quad * 16)      ^ ((rowA & 7) << 4));
    const int offA1 = rowA * 128 + ((quad * 16 + 64) ^ ((rowA & 7) << 4));
    const int offB0 = rowB * 128 + ((quad * 16)      ^ ((rowB & 7) << 4));
    const int offB1 = rowB * 128 + ((quad * 16 + 64) ^ ((rowB & 7) << 4));

    #pragma unroll
    for (int es = 0; es < 64; ++es) {
        const int cur = es & 1;
        if (es < 63) {
            if (cur == 0) { gld_lds16(srcA + (size_t)(es + 1) * 65536, dA1);
                            gld_lds16(srcB + (size_t)(es + 1) * 65536, dB1); }
            else          { gld_lds16(srcA + (size_t)(es + 1) * 65536, dA0);
                            gld_lds16(srcB + (size_t)(es + 1) * 65536, dB0); }
            asm volatile("s_waitcnt vmcnt(2)" ::: "memory");
        } else {
            asm volatile("s_waitcnt vmcnt(0)" ::: "memory");
        }
        asm volatile("s_barrier" ::: "memory");

        const char* a = (const char*)As[cur];
        const char* b = (const char*)Bs[cur];
        bf16x8 a0 = *(const bf16x8*)(a + offA0);
        bf16x8 a1 = *(const bf16x8*)(a + offA1);
        bf16x8 b0 = *(const bf16x8*)(b + offB0);
        bf16x8 b1 = *(const bf16x8*)(b + offB1);
        f32x4 z = {0.f, 0.f, 0.f, 0.f};
        z = __builtin_amdgcn_mfma_f32_16x16x32_bf16(a0, b0, z, 0, 0, 0);
        z = __builtin_amdgcn_mfma_f32_16x16x32_bf16(a1, b1, z, 0, 0, 0);

        const int dw = es >> 3, sh = (es & 7) * 4;
        #pragma unroll
        for (int r = 0; r < 4; ++r) {
            int t    = (sp[r][dw] >> sh) & 15;
            int gl   = mh * 16 + quad * 4 + r;
            int scol = (nh * 16 + lr) ^ ((t & 7) << 2);
            accs[(gl * 16 + t) * 32 + scol] += z[r];
        }
        asm volatile("s_barrier" ::: "memory");
    }
    __syncthreads();
    #pragma unroll
    for (int i = 0; i < 16; ++i) {
        int fi = i * 256 + tid;
        int row = fi >> 3, q = fi & 7;
        int scol4 = (q * 4) ^ ((row & 7) << 2);
        f32x4 v = *(f32x4*)(accs + row * 32 + scol4);
        __builtin_nontemporal_store(v, (f32x4*)(out + (size_t)(g0 * 16 + row) * DM + d0 + q * 4));
    }
}

extern "C" void kernel_launch(void* const* d_in, const int* in_sizes, int n_in,
                              void* d_out, int out_size, void* d_ws, size_t ws_size,
                              hipStream_t stream) {
    const float* x    = (const float*)d_in[0];
    const float* ctrl = (const float*)d_in[1];
    const float* f1   = (const float*)d_in[2];
    const float* f2   = (const float*)d_in[3];
    const float* bias = (const float*)d_in[4];
    float* out = (float*)d_out;

    char* ws = (char*)d_ws;
    bf16*     f1p   = (bf16*)(ws);                  // 8,388,608 B
    bf16*     f2t   = (bf16*)(ws + 8388608);        // 8,388,608 B
    bf16*     inner = (bf16*)(ws + 16777216);       // 8,388,608 B
    int*      sel   = (int*)(ws + 25165824);        //   262,144 B
    unsigned* selp  = (unsigned*)(ws + 25427968);   //    32,768 B

    hipLaunchKernelGGL(k0_transpose, dim3(16, 64), dim3(256), 0, stream, f1, f2, f1p, f2t);
    hipLaunchKernelGGL(k1_logits,    dim3(1024),   dim3(256), 0, stream, x, ctrl, sel, selp);
    hipLaunchKernelGGL(k2_ffn1,      dim3(8, 64),  dim3(256), 0, stream, x, f1p, bias, sel, inner);
    hipLaunchKernelGGL(k3_ffn2,      dim3(32, 32), dim3(256), 0, stream, inner, f2t, selp, out);
}